// Round 1
// baseline (93.432 us; speedup 1.0000x reference)
//
#include <hip/hip_runtime.h>

#define PAD 4

// out[n,c,i,j] = x[n,c, clamp(i+hs[n]-PAD,0,H-1), clamp(j+ws[n]-PAD,0,W-1)]
// Shapes fixed by the problem: N=256, C=12, H=128, W=128, fp32.

__global__ __launch_bounds__(256) void random_shift_kernel(
    const float* __restrict__ x,
    const int*   __restrict__ h_starts,
    const int*   __restrict__ w_starts,
    float*       __restrict__ out,
    int total4)
{
    constexpr int W = 128, H = 128, C = 12;
    int idx = blockIdx.x * blockDim.x + threadIdx.x;
    if (idx >= total4) return;

    int elem = idx << 2;                 // element index of first of 4 outputs
    int j0   = elem & (W - 1);           // output column (multiple of 4)
    int i    = (elem >> 7) & (H - 1);    // output row
    int nc   = elem >> 14;               // n*C + c  (H*W = 2^14)
    int n    = nc / C;

    int ws = w_starts[n] - PAD;          // shift in [-4, 4]
    int hs = h_starts[n] - PAD;

    int si = i + hs;
    si = si < 0 ? 0 : (si > H - 1 ? H - 1 : si);

    const float* __restrict__ src_row = x + (size_t)nc * (H * W) + (size_t)si * W;

    float4 v;
    int j;
    j = j0 + 0 + ws; j = j < 0 ? 0 : (j > W - 1 ? W - 1 : j); v.x = src_row[j];
    j = j0 + 1 + ws; j = j < 0 ? 0 : (j > W - 1 ? W - 1 : j); v.y = src_row[j];
    j = j0 + 2 + ws; j = j < 0 ? 0 : (j > W - 1 ? W - 1 : j); v.z = src_row[j];
    j = j0 + 3 + ws; j = j < 0 ? 0 : (j > W - 1 ? W - 1 : j); v.w = src_row[j];

    *reinterpret_cast<float4*>(out + elem) = v;
}

extern "C" void kernel_launch(void* const* d_in, const int* in_sizes, int n_in,
                              void* d_out, int out_size, void* d_ws, size_t ws_size,
                              hipStream_t stream) {
    const float* x        = (const float*)d_in[0];
    const int*   h_starts = (const int*)d_in[1];
    const int*   w_starts = (const int*)d_in[2];
    float*       out      = (float*)d_out;

    const int total  = 256 * 12 * 128 * 128;   // = out_size
    const int total4 = total >> 2;             // float4 stores
    const int block  = 256;
    const int grid   = (total4 + block - 1) / block;  // 12288 blocks

    random_shift_kernel<<<grid, block, 0, stream>>>(x, h_starts, w_starts, out, total4);
}

// Round 2
// 83.469 us; speedup vs baseline: 1.1194x; 1.1194x over previous
//
#include <hip/hip_runtime.h>

#define PAD 4

// out[n,c,i,j] = x[n,c, clamp(i+hs[n]-PAD,0,H-1), clamp(j+ws[n]-PAD,0,W-1)]
// N=256, C=12, H=128, W=128, fp32.
//
// Read-side vectorization: ws is wave-uniform (a wave spans 1024 consecutive
// elements, always within one (n,c) plane). Interior threads (window fully
// inside [0,127]) load 1-2 ALIGNED float4 and realign in registers via a
// uniform branch on s = sj&3. Edge threads (<=1 per 32-thread row) fall back
// to 4 clamped scalar loads.

__global__ __launch_bounds__(256) void random_shift_kernel(
    const float* __restrict__ x,
    const int*   __restrict__ h_starts,
    const int*   __restrict__ w_starts,
    float*       __restrict__ out,
    int total4)
{
    constexpr int W = 128, H = 128, C = 12;
    int idx = blockIdx.x * blockDim.x + threadIdx.x;
    if (idx >= total4) return;

    int elem = idx << 2;                 // first of 4 output elements
    int j0   = elem & (W - 1);           // output column (multiple of 4)
    int i    = (elem >> 7) & (H - 1);    // output row
    int nc   = elem >> 14;               // n*C + c
    int n    = nc / C;

    int ws = w_starts[n] - PAD;          // [-4, 4], wave-uniform
    int hs = h_starts[n] - PAD;

    int si = i + hs;
    si = si < 0 ? 0 : (si > H - 1 ? H - 1 : si);

    const float* __restrict__ src_row = x + (size_t)nc * (H * W) + (size_t)si * W;

    float4 v;
    int sj = j0 + ws;                    // source start column, in [-4, 128]

    if (sj >= 0 && sj <= W - 4) {
        // Fast path: no clamping needed; realign from aligned quads.
        const float4* __restrict__ src4 = reinterpret_cast<const float4*>(src_row);
        int q = sj >> 2;                 // aligned quad index, [0, 31]
        int s = sj & 3;                  // wave-uniform sub-quad shift
        float4 A = src4[q];
        if (s == 0) {
            v = A;
        } else {
            float4 B = src4[q + 1];      // q <= 30 here (sj <= 124, s >= 1)
            if (s == 1)      v = make_float4(A.y, A.z, A.w, B.x);
            else if (s == 2) v = make_float4(A.z, A.w, B.x, B.y);
            else             v = make_float4(A.w, B.x, B.y, B.z);
        }
    } else {
        // Edge path: per-element column clamp.
        int j;
        j = sj + 0; j = j < 0 ? 0 : (j > W - 1 ? W - 1 : j); v.x = src_row[j];
        j = sj + 1; j = j < 0 ? 0 : (j > W - 1 ? W - 1 : j); v.y = src_row[j];
        j = sj + 2; j = j < 0 ? 0 : (j > W - 1 ? W - 1 : j); v.z = src_row[j];
        j = sj + 3; j = j < 0 ? 0 : (j > W - 1 ? W - 1 : j); v.w = src_row[j];
    }

    *reinterpret_cast<float4*>(out + elem) = v;
}

extern "C" void kernel_launch(void* const* d_in, const int* in_sizes, int n_in,
                              void* d_out, int out_size, void* d_ws, size_t ws_size,
                              hipStream_t stream) {
    const float* x        = (const float*)d_in[0];
    const int*   h_starts = (const int*)d_in[1];
    const int*   w_starts = (const int*)d_in[2];
    float*       out      = (float*)d_out;

    const int total  = 256 * 12 * 128 * 128;
    const int total4 = total >> 2;
    const int block  = 256;
    const int grid   = (total4 + block - 1) / block;   // 12288 blocks

    random_shift_kernel<<<grid, block, 0, stream>>>(x, h_starts, w_starts, out, total4);
}

// Round 3
// 63.156 us; speedup vs baseline: 1.4794x; 1.3216x over previous
//
#include <hip/hip_runtime.h>

#define PAD 4

// out[n,c,i,j] = x[n,c, clamp(i+hs[n]-PAD,0,H-1), clamp(j+ws[n]-PAD,0,W-1)]
// N=256, C=12, H=128, W=128, fp32.
//
// Round 3 structure:
//  - 2D grid: blockIdx.y = n  -> hs/ws are wave-uniform scalar loads, no
//    integer division anywhere.
//  - 4 float4 per thread, block-strided (stride 256 f4) -> coalesced, 4
//    independent load->store chains, setup amortized.
//  - Read realign: interior threads load 1-2 ALIGNED float4 and realign in
//    registers (s = sj&3 is wave-uniform); edge threads (<=1 per 32-quad row)
//    take the 4-scalar-clamped-load path under exec mask.
//  - Nontemporal stores: output is write-once, keep it out of L2/L3.

using vf4 = __attribute__((ext_vector_type(4))) float;

__global__ __launch_bounds__(256) void random_shift_kernel(
    const float* __restrict__ x,
    const int*   __restrict__ h_starts,
    const int*   __restrict__ w_starts,
    float*       __restrict__ out)
{
    constexpr int W = 128, H = 128, C = 12;
    constexpr int PLANE  = H * W;        // 16384 floats
    constexpr int SAMPLE = C * PLANE;    // 196608 floats = 49152 float4

    const int n  = blockIdx.y;           // sample index (uniform)
    const int ws = w_starts[n] - PAD;    // [-4, 4], scalar
    const int hs = h_starts[n] - PAD;

    const float* __restrict__ xs = x   + (size_t)n * SAMPLE;
    float*       __restrict__ os = out + (size_t)n * SAMPLE;

    const int t       = threadIdx.x;
    const int base_f4 = blockIdx.x << 10;   // 1024 float4 per block

    #pragma unroll
    for (int k = 0; k < 4; ++k) {
        int f4idx = base_f4 + (k << 8) + t;     // [0, 49152)
        int elem  = f4idx << 2;
        int j0    = elem & (W - 1);             // output column (mult of 4)
        int i     = (elem >> 7) & (H - 1);      // output row
        int poff  = elem & ~(PLANE - 1);        // c * PLANE

        int si = i + hs;
        si = si < 0 ? 0 : (si > H - 1 ? H - 1 : si);

        const float* __restrict__ src_row = xs + poff + si * W;

        vf4 v;
        int sj = j0 + ws;                       // [-4, 128]

        if (sj >= 0 && sj <= W - 4) {
            const vf4* __restrict__ src4 = reinterpret_cast<const vf4*>(src_row);
            int q = sj >> 2;                    // [0, 31]
            int s = sj & 3;                     // wave-uniform
            vf4 A = src4[q];
            if (s == 0) {
                v = A;
            } else {
                vf4 B = src4[q + 1];            // q <= 30 when s >= 1
                if (s == 1)      v = (vf4){A.y, A.z, A.w, B.x};
                else if (s == 2) v = (vf4){A.z, A.w, B.x, B.y};
                else             v = (vf4){A.w, B.x, B.y, B.z};
            }
        } else {
            int j;
            j = sj + 0; j = j < 0 ? 0 : (j > W - 1 ? W - 1 : j); v.x = src_row[j];
            j = sj + 1; j = j < 0 ? 0 : (j > W - 1 ? W - 1 : j); v.y = src_row[j];
            j = sj + 2; j = j < 0 ? 0 : (j > W - 1 ? W - 1 : j); v.z = src_row[j];
            j = sj + 3; j = j < 0 ? 0 : (j > W - 1 ? W - 1 : j); v.w = src_row[j];
        }

        __builtin_nontemporal_store(v, reinterpret_cast<vf4*>(os + elem));
    }
}

extern "C" void kernel_launch(void* const* d_in, const int* in_sizes, int n_in,
                              void* d_out, int out_size, void* d_ws, size_t ws_size,
                              hipStream_t stream) {
    const float* x        = (const float*)d_in[0];
    const int*   h_starts = (const int*)d_in[1];
    const int*   w_starts = (const int*)d_in[2];
    float*       out      = (float*)d_out;

    // 49152 float4 per sample / (256 threads * 4 f4) = 48 blocks per sample
    dim3 grid(48, 256);
    dim3 block(256);

    random_shift_kernel<<<grid, block, 0, stream>>>(x, h_starts, w_starts, out);
}